// Round 2
// baseline (1074.527 us; speedup 1.0000x reference)
//
#include <hip/hip_runtime.h>
#include <hip/hip_bf16.h>

#define N_NODES 50000
#define N_EDGES 800000
#define ET (N_EDGES + N_NODES)   // with self-loops
#define F_IN 128
#define HH 128                   // HEADS*HID
#define HEADS 4
#define HID 32
#define NCLS 16
#define NEG 0.2f

__device__ __forceinline__ float lrelu(float x) { return x > 0.f ? x : NEG * x; }

// float atomic max via int/uint bit tricks; dest must be initialized to -inf
__device__ __forceinline__ void atomicMaxF(float* addr, float value) {
    if (value >= 0.f)
        atomicMax((int*)addr, __float_as_int(value));
    else
        atomicMin((unsigned int*)addr, __float_as_uint(value));
}

__global__ void k_fill_neginf(float* p, int n) {
    int i = blockIdx.x * blockDim.x + threadIdx.x;
    if (i < n) p[i] = __int_as_float(0xff800000);
}

// h1 = x @ W1, plus per-head attention logits. grid: N_NODES blocks x 128 thr
__global__ void k_gemm1(const float* __restrict__ x, const float* __restrict__ W1,
                        const float* __restrict__ a_s, const float* __restrict__ a_d,
                        float* __restrict__ h1, float* __restrict__ al_s,
                        float* __restrict__ al_d) {
    int n = blockIdx.x;
    int j = threadIdx.x;  // 0..127 output feature (head = j>>5, d = j&31)
    __shared__ float xs[F_IN];
    __shared__ float rs[HH], rd[HH];
    xs[j] = x[n * F_IN + j];
    __syncthreads();
    float acc = 0.f;
#pragma unroll
    for (int k = 0; k < F_IN; ++k)
        acc = fmaf(xs[k], W1[k * HH + j], acc);
    h1[n * HH + j] = acc;
    rs[j] = acc * a_s[j];   // a_src1 flat [h*32+d] matches j layout
    rd[j] = acc * a_d[j];
    __syncthreads();
    for (int off = 16; off > 0; off >>= 1) {
        if ((j & 31) < off) { rs[j] += rs[j + off]; rd[j] += rd[j + off]; }
        __syncthreads();
    }
    if ((j & 31) == 0) {
        al_s[n * HEADS + (j >> 5)] = rs[j];
        al_d[n * HEADS + (j >> 5)] = rd[j];
    }
}

__device__ __forceinline__ void edge_sd(const int* __restrict__ ei, int i, int& s, int& d) {
    if (i < N_EDGES) { s = ei[i]; d = ei[N_EDGES + i]; }
    else             { s = i - N_EDGES; d = s; }
}

__global__ void k_edge_max1(const int* __restrict__ ei, const float* __restrict__ al_s,
                            const float* __restrict__ al_d, float* __restrict__ m1) {
    int i = blockIdx.x * blockDim.x + threadIdx.x;
    if (i >= ET) return;
    int s, d; edge_sd(ei, i, s, d);
    float4 AS = ((const float4*)al_s)[s];
    float4 AD = ((const float4*)al_d)[d];
    atomicMaxF(&m1[d * 4 + 0], lrelu(AS.x + AD.x));
    atomicMaxF(&m1[d * 4 + 1], lrelu(AS.y + AD.y));
    atomicMaxF(&m1[d * 4 + 2], lrelu(AS.z + AD.z));
    atomicMaxF(&m1[d * 4 + 3], lrelu(AS.w + AD.w));
}

__global__ void k_edge_sum1(const int* __restrict__ ei, const float* __restrict__ al_s,
                            const float* __restrict__ al_d, const float* __restrict__ m1,
                            float* __restrict__ den1) {
    int i = blockIdx.x * blockDim.x + threadIdx.x;
    if (i >= ET) return;
    int s, d; edge_sd(ei, i, s, d);
    float4 AS = ((const float4*)al_s)[s];
    float4 AD = ((const float4*)al_d)[d];
    float4 M  = ((const float4*)m1)[d];
    atomicAdd(&den1[d * 4 + 0], __expf(lrelu(AS.x + AD.x) - M.x));
    atomicAdd(&den1[d * 4 + 1], __expf(lrelu(AS.y + AD.y) - M.y));
    atomicAdd(&den1[d * 4 + 2], __expf(lrelu(AS.z + AD.z) - M.z));
    atomicAdd(&den1[d * 4 + 3], __expf(lrelu(AS.w + AD.w) - M.w));
}

// 2 edges per 256-thread block; 128 features per edge
__global__ void k_scatter1(const int* __restrict__ ei, const float* __restrict__ al_s,
                           const float* __restrict__ al_d, const float* __restrict__ m1,
                           const float* __restrict__ den1, const float* __restrict__ h1,
                           float* __restrict__ agg1) {
    __shared__ float alpha[2][HEADS];
    __shared__ int ss[2], dd[2];
    int t = threadIdx.x;
    int base = blockIdx.x * 2;
    if (t < 2 * HEADS) {
        int le = t >> 2, h = t & 3;
        int i = base + le;
        if (i < ET) {
            int s, d; edge_sd(ei, i, s, d);
            if (h == 0) { ss[le] = s; dd[le] = d; }
            float e = lrelu(al_s[s * 4 + h] + al_d[d * 4 + h]);
            alpha[le][h] = __expf(e - m1[d * 4 + h]) / den1[d * 4 + h];
        }
    }
    __syncthreads();
    int le = t >> 7, j = t & 127;
    int i = base + le;
    if (i < ET) {
        int s = ss[le], d = dd[le];
        float v = h1[s * HH + j] * alpha[le][j >> 5];
        atomicAdd(&agg1[d * HH + j], v);
    }
}

__global__ void k_bias_elu1(float* __restrict__ agg1, const float* __restrict__ b1) {
    int i = blockIdx.x * blockDim.x + threadIdx.x;
    if (i >= N_NODES * HH) return;
    float v = agg1[i] + b1[i & 127];
    agg1[i] = v > 0.f ? v : __expf(v) - 1.f;  // ELU (in place -> h1_act)
}

// h2 = h1_act @ W2 + layer-2 attention logits. 16 nodes x 16 cls per block.
__global__ void k_gemm2(const float* __restrict__ h1a, const float* __restrict__ W2,
                        const float* __restrict__ a_s2, const float* __restrict__ a_d2,
                        float* __restrict__ h2, float* __restrict__ al_s2,
                        float* __restrict__ al_d2) {
    __shared__ float hs[16 * 129];
    __shared__ float w2[F_IN * NCLS];
    __shared__ float red[256];
    int t = threadIdx.x;
    int nb = blockIdx.x * 16;
    for (int idx = t; idx < F_IN * NCLS; idx += 256) w2[idx] = W2[idx];
    for (int idx = t; idx < 16 * F_IN; idx += 256) {
        int ln = idx >> 7, k = idx & 127;
        int n = nb + ln;
        hs[ln * 129 + k] = (n < N_NODES) ? h1a[n * F_IN + k] : 0.f;
    }
    __syncthreads();
    int ln = t >> 4, c = t & 15;
    float acc = 0.f;
#pragma unroll
    for (int k = 0; k < F_IN; ++k)
        acc = fmaf(hs[ln * 129 + k], w2[k * NCLS + c], acc);
    int n = nb + ln;
    if (n < N_NODES) h2[n * NCLS + c] = acc;
    red[t] = acc * a_s2[c];
    __syncthreads();
    for (int off = 8; off > 0; off >>= 1) { if (c < off) red[t] += red[t + off]; __syncthreads(); }
    float asv = red[ln * 16];
    __syncthreads();
    red[t] = acc * a_d2[c];
    __syncthreads();
    for (int off = 8; off > 0; off >>= 1) { if (c < off) red[t] += red[t + off]; __syncthreads(); }
    if (c == 0 && n < N_NODES) { al_s2[n] = asv; al_d2[n] = red[t]; }
}

__global__ void k_edge_max2(const int* __restrict__ ei, const float* __restrict__ al_s2,
                            const float* __restrict__ al_d2, float* __restrict__ m2) {
    int i = blockIdx.x * blockDim.x + threadIdx.x;
    if (i >= ET) return;
    int s, d; edge_sd(ei, i, s, d);
    atomicMaxF(&m2[d], lrelu(al_s2[s] + al_d2[d]));
}

__global__ void k_edge_sum2(const int* __restrict__ ei, const float* __restrict__ al_s2,
                            const float* __restrict__ al_d2, const float* __restrict__ m2,
                            float* __restrict__ den2) {
    int i = blockIdx.x * blockDim.x + threadIdx.x;
    if (i >= ET) return;
    int s, d; edge_sd(ei, i, s, d);
    atomicAdd(&den2[d], __expf(lrelu(al_s2[s] + al_d2[d]) - m2[d]));
}

// 16 edges per 256-thread block; 16 features per edge
__global__ void k_scatter2(const int* __restrict__ ei, const float* __restrict__ al_s2,
                           const float* __restrict__ al_d2, const float* __restrict__ m2,
                           const float* __restrict__ den2, const float* __restrict__ h2,
                           float* __restrict__ agg2) {
    __shared__ float alpha[16];
    __shared__ int ss[16], dd[16];
    int t = threadIdx.x;
    int base = blockIdx.x * 16;
    if (t < 16) {
        int i = base + t;
        if (i < ET) {
            int s, d; edge_sd(ei, i, s, d);
            ss[t] = s; dd[t] = d;
            float e = lrelu(al_s2[s] + al_d2[d]);
            alpha[t] = __expf(e - m2[d]) / den2[d];
        }
    }
    __syncthreads();
    int le = t >> 4, c = t & 15;
    int i = base + le;
    if (i < ET)
        atomicAdd(&agg2[dd[le] * NCLS + c], h2[ss[le] * NCLS + c] * alpha[le]);
}

// out = log_softmax(agg2 + b2). 16 nodes x 16 cls per block.
__global__ void k_out(const float* __restrict__ agg2, const float* __restrict__ b2,
                      float* __restrict__ out) {
    __shared__ float red[256];
    int t = threadIdx.x;
    int ln = t >> 4, c = t & 15;
    int n = blockIdx.x * 16 + ln;
    float v = (n < N_NODES) ? agg2[n * NCLS + c] + b2[c] : 0.f;
    red[t] = v;
    __syncthreads();
    for (int off = 8; off > 0; off >>= 1) { if (c < off) red[t] = fmaxf(red[t], red[t + off]); __syncthreads(); }
    float m = red[ln * 16];
    __syncthreads();
    red[t] = __expf(v - m);
    __syncthreads();
    for (int off = 8; off > 0; off >>= 1) { if (c < off) red[t] += red[t + off]; __syncthreads(); }
    float lse = m + __logf(red[ln * 16]);
    if (n < N_NODES) out[n * NCLS + c] = v - lse;
}

extern "C" void kernel_launch(void* const* d_in, const int* in_sizes, int n_in,
                              void* d_out, int out_size, void* d_ws, size_t ws_size,
                              hipStream_t stream) {
    const float* x   = (const float*)d_in[0];
    const int*   ei  = (const int*)d_in[1];
    const float* W1  = (const float*)d_in[2];
    const float* as1 = (const float*)d_in[3];
    const float* ad1 = (const float*)d_in[4];
    const float* b1  = (const float*)d_in[5];
    const float* W2  = (const float*)d_in[6];
    const float* as2 = (const float*)d_in[7];
    const float* ad2 = (const float*)d_in[8];
    const float* b2  = (const float*)d_in[9];
    float* out = (float*)d_out;
    char* ws = (char*)d_ws;

    float* h1   = (float*)(ws);                 // N*128
    float* agg1 = (float*)(ws + 25600000);      // N*128 (becomes h1_act in place)
    float* alS1 = (float*)(ws + 51200000);      // N*4
    float* alD1 = (float*)(ws + 52000000);      // N*4
    float* m1   = (float*)(ws + 52800000);      // N*4
    float* den1 = (float*)(ws + 53600000);      // N*4
    float* h2   = (float*)(ws + 54400000);      // N*16
    float* alS2 = (float*)(ws + 57600000);      // N
    float* alD2 = (float*)(ws + 57800000);      // N
    float* m2   = (float*)(ws + 58000000);      // N
    float* den2 = (float*)(ws + 58200000);      // N
    float* agg2 = (float*)(ws + 58400000);      // N*16   (total 61.6 MB)

    hipMemsetAsync(agg1, 0, (size_t)N_NODES * HH * 4, stream);
    hipMemsetAsync(den1, 0, (size_t)N_NODES * HEADS * 4, stream);
    hipMemsetAsync(den2, 0, (size_t)N_NODES * 4, stream);
    hipMemsetAsync(agg2, 0, (size_t)N_NODES * NCLS * 4, stream);
    k_fill_neginf<<<(N_NODES * HEADS + 255) / 256, 256, 0, stream>>>(m1, N_NODES * HEADS);
    k_fill_neginf<<<(N_NODES + 255) / 256, 256, 0, stream>>>(m2, N_NODES);

    k_gemm1<<<N_NODES, 128, 0, stream>>>(x, W1, as1, ad1, h1, alS1, alD1);
    k_edge_max1<<<(ET + 255) / 256, 256, 0, stream>>>(ei, alS1, alD1, m1);
    k_edge_sum1<<<(ET + 255) / 256, 256, 0, stream>>>(ei, alS1, alD1, m1, den1);
    k_scatter1<<<(ET + 1) / 2, 256, 0, stream>>>(ei, alS1, alD1, m1, den1, h1, agg1);
    k_bias_elu1<<<(N_NODES * HH + 255) / 256, 256, 0, stream>>>(agg1, b1);
    k_gemm2<<<(N_NODES + 15) / 16, 256, 0, stream>>>(agg1, W2, as2, ad2, h2, alS2, alD2);
    k_edge_max2<<<(ET + 255) / 256, 256, 0, stream>>>(ei, alS2, alD2, m2);
    k_edge_sum2<<<(ET + 255) / 256, 256, 0, stream>>>(ei, alS2, alD2, m2, den2);
    k_scatter2<<<(ET + 15) / 16, 256, 0, stream>>>(ei, alS2, alD2, m2, den2, h2, agg2);
    k_out<<<(N_NODES + 15) / 16, 256, 0, stream>>>(agg2, b2, out);
}

// Round 3
// 487.475 us; speedup vs baseline: 2.2043x; 2.2043x over previous
//
#include <hip/hip_runtime.h>
#include <hip/hip_bf16.h>

#define N_NODES 50000
#define N_EDGES 800000
#define ET (N_EDGES + N_NODES)   // with self-loops
#define F_IN 128
#define HH 128                   // HEADS*HID
#define HEADS 4
#define HID 32
#define NCLS 16
#define NEG 0.2f
#define NEG_BIG (-1e30f)

__device__ __forceinline__ float lrelu(float x) { return x > 0.f ? x : NEG * x; }

__device__ __forceinline__ void edge_sd(const int* __restrict__ ei, int i, int& s, int& d) {
    if (i < N_EDGES) { s = ei[i]; d = ei[N_EDGES + i]; }
    else             { s = i - N_EDGES; d = s; }
}

// ---------------- CSR build ----------------
__global__ void k_deg(const int* __restrict__ ei, int* __restrict__ deg) {
    int i = blockIdx.x * blockDim.x + threadIdx.x;
    if (i >= ET) return;
    int s, d; edge_sd(ei, i, s, d);
    atomicAdd(&deg[d], 1);
}

// single block, 1024 threads: exclusive scan of deg -> offs (and cursor copy)
__global__ void k_scan(const int* __restrict__ deg, int* __restrict__ offs,
                       int* __restrict__ cursor) {
    __shared__ int part[1024];
    int t = threadIdx.x;
    const int CH = (N_NODES + 1023) / 1024;  // 49
    int base = t * CH;
    int sum = 0;
    for (int i = 0; i < CH; ++i) {
        int idx = base + i;
        if (idx < N_NODES) sum += deg[idx];
    }
    part[t] = sum;
    __syncthreads();
    for (int off = 1; off < 1024; off <<= 1) {
        int v = (t >= off) ? part[t - off] : 0;
        __syncthreads();
        part[t] += v;
        __syncthreads();
    }
    int run = (t == 0) ? 0 : part[t - 1];
    for (int i = 0; i < CH; ++i) {
        int idx = base + i;
        if (idx < N_NODES) { offs[idx] = run; cursor[idx] = run; run += deg[idx]; }
    }
    if (t == 1023) offs[N_NODES] = part[1023];
}

__global__ void k_fill(const int* __restrict__ ei, int* __restrict__ cursor,
                       int* __restrict__ esrc) {
    int i = blockIdx.x * blockDim.x + threadIdx.x;
    if (i >= ET) return;
    int s, d; edge_sd(ei, i, s, d);
    int pos = atomicAdd(&cursor[d], 1);
    esrc[pos] = s;
}

// ---------------- layer 1 GEMM: h1 = x @ W1, + attention logits ----------------
// 16 nodes per 256-thread block. Thread t: feature jj=t&127, nodes half*8..half*8+7.
__global__ void k_gemm1(const float* __restrict__ x, const float* __restrict__ W1,
                        const float* __restrict__ a_s, const float* __restrict__ a_d,
                        float* __restrict__ h1, float* __restrict__ al_s,
                        float* __restrict__ al_d) {
    __shared__ float xs[16 * F_IN];      // 8 KB
    __shared__ float hv[16 * HH];        // 8 KB (raw h1 values for reductions)
    int t = threadIdx.x;
    int nb = blockIdx.x * 16;
    // load 16 x-rows, coalesced float4
    const float4* xv = (const float4*)(x + (size_t)nb * F_IN);
    float4* xsv = (float4*)xs;
    for (int idx = t; idx < 16 * F_IN / 4; idx += 256) xsv[idx] = xv[idx];
    __syncthreads();
    int jj = t & 127, half = t >> 7;
    float acc[8] = {0, 0, 0, 0, 0, 0, 0, 0};
    for (int k = 0; k < F_IN; ++k) {
        float w = W1[k * HH + jj];
#pragma unroll
        for (int nd = 0; nd < 8; ++nd)
            acc[nd] = fmaf(xs[(half * 8 + nd) * F_IN + k], w, acc[nd]);  // LDS broadcast
    }
#pragma unroll
    for (int nd = 0; nd < 8; ++nd) {
        int n = half * 8 + nd;
        h1[(size_t)(nb + n) * HH + jj] = acc[nd];
        hv[n * HH + jj] = acc[nd];
    }
    __syncthreads();
    // 64 threads: (node, head) sums over 32 dims
    if (t < 64) {
        int n = t >> 2, h = t & 3;
        float s1 = 0.f, s2 = 0.f;
        for (int i = 0; i < HID; ++i) {
            float v = hv[n * HH + h * HID + i];
            s1 = fmaf(v, a_s[h * HID + i], s1);
            s2 = fmaf(v, a_d[h * HID + i], s2);
        }
        al_s[(nb + n) * HEADS + h] = s1;
        al_d[(nb + n) * HEADS + h] = s2;
    }
}

// ---------------- layer 1 aggregate: wave per dst node, no atomics ----------------
__global__ void k_agg1(const int* __restrict__ esrc, const int* __restrict__ offs,
                       const float* __restrict__ alS, const float* __restrict__ alD,
                       const float* __restrict__ h1, const float* __restrict__ b1,
                       float* __restrict__ h1a) {
    int gid = blockIdx.x * blockDim.x + threadIdx.x;
    int n = gid >> 6;
    int lane = threadIdx.x & 63;
    if (n >= N_NODES) return;
    int off = offs[n], end = offs[n + 1];
    int h = lane >> 4;                  // head (same for phase A slot grouping and feature pair)
    float ad = alD[n * 4 + h];
    // phase A: online softmax over this node's edges; slot = lane & 15
    float m = NEG_BIG, ssum = 0.f;
    for (int e = off + (lane & 15); e < end; e += 16) {
        int s = esrc[e];
        float ev = lrelu(alS[s * 4 + h] + ad);
        if (ev > m) { ssum = ssum * __expf(m - ev) + 1.f; m = ev; }
        else        { ssum += __expf(ev - m); }
    }
#pragma unroll
    for (int w = 1; w < 16; w <<= 1) {
        float mo = __shfl_xor(m, w);
        float so = __shfl_xor(ssum, w);
        float mn = fmaxf(m, mo);
        ssum = ssum * __expf(m - mn) + so * __expf(mo - mn);
        m = mn;
    }
    float inv_den = 1.f / ssum;
    // phase B: features 2*lane, 2*lane+1  (head = lane>>4 == h)
    const float2* h1v = (const float2*)h1;
    float2 acc = make_float2(0.f, 0.f);
    int e = off;
    int s = esrc[e];
    for (; e < end; ) {
        int e1 = e + 1;
        int s1 = (e1 < end) ? esrc[e1] : 0;
        float as = alS[s * 4 + h];
        float2 hvv = h1v[(size_t)s * 64 + lane];
        float ev = lrelu(as + ad);
        float alpha = __expf(ev - m) * inv_den;
        acc.x = fmaf(hvv.x, alpha, acc.x);
        acc.y = fmaf(hvv.y, alpha, acc.y);
        s = s1; e = e1;
    }
    // bias + ELU, write once
    float vx = acc.x + b1[2 * lane];
    float vy = acc.y + b1[2 * lane + 1];
    vx = vx > 0.f ? vx : __expf(vx) - 1.f;
    vy = vy > 0.f ? vy : __expf(vy) - 1.f;
    ((float2*)h1a)[(size_t)n * 64 + lane] = make_float2(vx, vy);
}

// ---------------- layer 2 GEMM: h2 = h1a @ W2, + logits ----------------
__global__ void k_gemm2(const float* __restrict__ h1a, const float* __restrict__ W2,
                        const float* __restrict__ a_s2, const float* __restrict__ a_d2,
                        float* __restrict__ h2, float* __restrict__ al_s2,
                        float* __restrict__ al_d2) {
    __shared__ float hs[16 * 129];
    __shared__ float w2[F_IN * NCLS];
    __shared__ float red[256];
    int t = threadIdx.x;
    int nb = blockIdx.x * 16;
    for (int idx = t; idx < F_IN * NCLS; idx += 256) w2[idx] = W2[idx];
    for (int idx = t; idx < 16 * F_IN; idx += 256) {
        int ln = idx >> 7, k = idx & 127;
        hs[ln * 129 + k] = h1a[(size_t)(nb + ln) * F_IN + k];
    }
    __syncthreads();
    int ln = t >> 4, c = t & 15;
    float acc = 0.f;
#pragma unroll
    for (int k = 0; k < F_IN; ++k)
        acc = fmaf(hs[ln * 129 + k], w2[k * NCLS + c], acc);
    int n = nb + ln;
    h2[(size_t)n * NCLS + c] = acc;
    red[t] = acc * a_s2[c];
    __syncthreads();
    for (int off = 8; off > 0; off >>= 1) { if (c < off) red[t] += red[t + off]; __syncthreads(); }
    float asv = red[ln * 16];
    __syncthreads();
    red[t] = acc * a_d2[c];
    __syncthreads();
    for (int off = 8; off > 0; off >>= 1) { if (c < off) red[t] += red[t + off]; __syncthreads(); }
    if (c == 0) { al_s2[n] = asv; al_d2[n] = red[t]; }
}

// ---------------- layer 2 aggregate + bias + log_softmax -> out ----------------
__global__ void k_agg2(const int* __restrict__ esrc, const int* __restrict__ offs,
                       const float* __restrict__ alS2, const float* __restrict__ alD2,
                       const float* __restrict__ h2, const float* __restrict__ b2,
                       float* __restrict__ out) {
    int gid = blockIdx.x * blockDim.x + threadIdx.x;
    int n = gid >> 6;
    int lane = threadIdx.x & 63;
    if (n >= N_NODES) return;
    int off = offs[n], end = offs[n + 1];
    float ad = alD2[n];
    // phase A: 64 slots online softmax
    float m = NEG_BIG, ssum = 0.f;
    for (int e = off + lane; e < end; e += 64) {
        int s = esrc[e];
        float ev = lrelu(alS2[s] + ad);
        if (ev > m) { ssum = ssum * __expf(m - ev) + 1.f; m = ev; }
        else        { ssum += __expf(ev - m); }
    }
#pragma unroll
    for (int w = 1; w < 64; w <<= 1) {
        float mo = __shfl_xor(m, w);
        float so = __shfl_xor(ssum, w);
        float mn = fmaxf(m, mo);
        ssum = ssum * __expf(m - mn) + so * __expf(mo - mn);
        m = mn;
    }
    float inv_den = 1.f / ssum;
    // phase B: class c = lane&15, edge sub-slot = lane>>4 (4-way)
    int c = lane & 15, sub = lane >> 4;
    float acc = 0.f;
    for (int e = off + sub; e < end; e += 4) {
        int s = esrc[e];
        float ev = lrelu(alS2[s] + ad);
        float alpha = __expf(ev - m) * inv_den;
        acc = fmaf(h2[(size_t)s * NCLS + c], alpha, acc);
    }
    acc += __shfl_xor(acc, 16);
    acc += __shfl_xor(acc, 32);
    float v = acc + b2[c];
    // log_softmax across the 16 classes (butterfly over class bits)
    float mx = v;
#pragma unroll
    for (int w = 1; w < 16; w <<= 1) mx = fmaxf(mx, __shfl_xor(mx, w));
    float ex = __expf(v - mx);
#pragma unroll
    for (int w = 1; w < 16; w <<= 1) ex += __shfl_xor(ex, w);
    float lse = mx + __logf(ex);
    if (lane < 16) out[(size_t)n * NCLS + lane] = v - lse;
}

extern "C" void kernel_launch(void* const* d_in, const int* in_sizes, int n_in,
                              void* d_out, int out_size, void* d_ws, size_t ws_size,
                              hipStream_t stream) {
    const float* x   = (const float*)d_in[0];
    const int*   ei  = (const int*)d_in[1];
    const float* W1  = (const float*)d_in[2];
    const float* as1 = (const float*)d_in[3];
    const float* ad1 = (const float*)d_in[4];
    const float* b1  = (const float*)d_in[5];
    const float* W2  = (const float*)d_in[6];
    const float* as2 = (const float*)d_in[7];
    const float* ad2 = (const float*)d_in[8];
    const float* b2  = (const float*)d_in[9];
    float* out = (float*)d_out;
    char* ws = (char*)d_ws;

    float* h1   = (float*)(ws);                 // N*128      = 25.6 MB
    float* h1a  = (float*)(ws + 25600000);      // N*128      = 25.6 MB
    float* alS1 = (float*)(ws + 51200000);      // N*4
    float* alD1 = (float*)(ws + 52000000);      // N*4
    float* h2   = (float*)(ws + 52800000);      // N*16       = 3.2 MB
    float* alS2 = (float*)(ws + 56000000);      // N
    float* alD2 = (float*)(ws + 56200000);      // N
    int*   deg  = (int*)  (ws + 56400000);      // N
    int*   offs = (int*)  (ws + 56600000);      // N+1
    int*   curs = (int*)  (ws + 56810000);      // N
    int*   esrc = (int*)  (ws + 57010000);      // ET         = 3.4 MB  (total ~60.4 MB)

    hipMemsetAsync(deg, 0, (size_t)N_NODES * 4, stream);
    k_deg<<<(ET + 255) / 256, 256, 0, stream>>>(ei, deg);
    k_scan<<<1, 1024, 0, stream>>>(deg, offs, curs);
    k_fill<<<(ET + 255) / 256, 256, 0, stream>>>(ei, curs, esrc);

    k_gemm1<<<N_NODES / 16, 256, 0, stream>>>(x, W1, as1, ad1, h1, alS1, alD1);
    k_agg1<<<(N_NODES * 64 + 255) / 256, 256, 0, stream>>>(esrc, offs, alS1, alD1, h1, b1, h1a);
    k_gemm2<<<N_NODES / 16, 256, 0, stream>>>(h1a, W2, as2, ad2, h2, alS2, alD2);
    k_agg2<<<(N_NODES * 64 + 255) / 256, 256, 0, stream>>>(esrc, offs, alS2, alD2, h2, b2, out);
}

// Round 4
// 372.755 us; speedup vs baseline: 2.8827x; 1.3078x over previous
//
#include <hip/hip_runtime.h>
#include <hip/hip_bf16.h>

#define N_NODES 50000
#define N_EDGES 800000
#define ET (N_EDGES + N_NODES)   // with self-loops
#define F_IN 128
#define HH 128                   // HEADS*HID
#define HEADS 4
#define HID 32
#define NCLS 16
#define NEG 0.2f
#define NEG_BIG (-1e30f)
#define NB_SCAN ((N_NODES + 255) / 256)   // 196

__device__ __forceinline__ float lrelu(float x) { return x > 0.f ? x : NEG * x; }

__device__ __forceinline__ void edge_sd(const int* __restrict__ ei, int i, int& s, int& d) {
    if (i < N_EDGES) { s = ei[i]; d = ei[N_EDGES + i]; }
    else             { s = i - N_EDGES; d = s; }
}

// ---------------- CSR build ----------------
__global__ void k_deg(const int* __restrict__ ei, int* __restrict__ deg) {
    int i = blockIdx.x * blockDim.x + threadIdx.x;
    if (i >= ET) return;
    int s, d; edge_sd(ei, i, s, d);
    atomicAdd(&deg[d], 1);
}

// phase 1: per-block exclusive scan of 256 degrees + block sum
__global__ void k_scan1(const int* __restrict__ deg, int* __restrict__ ex,
                        int* __restrict__ bsum) {
    __shared__ int sh[256];
    int t = threadIdx.x;
    int i = blockIdx.x * 256 + t;
    int v = (i < N_NODES) ? deg[i] : 0;
    sh[t] = v;
    __syncthreads();
    for (int off = 1; off < 256; off <<= 1) {
        int u = (t >= off) ? sh[t - off] : 0;
        __syncthreads();
        sh[t] += u;
        __syncthreads();
    }
    if (i < N_NODES) ex[i] = sh[t] - v;
    if (t == 255) bsum[blockIdx.x] = sh[255];
}

// phase 2: single tiny block scans the 196 block sums (exclusive)
__global__ void k_scan2(const int* __restrict__ bsum, int* __restrict__ boff) {
    __shared__ int sh[256];
    int t = threadIdx.x;
    int v = (t < NB_SCAN) ? bsum[t] : 0;
    sh[t] = v;
    __syncthreads();
    for (int off = 1; off < 256; off <<= 1) {
        int u = (t >= off) ? sh[t - off] : 0;
        __syncthreads();
        sh[t] += u;
        __syncthreads();
    }
    if (t < NB_SCAN) boff[t] = sh[t] - v;
}

// phase 3: combine
__global__ void k_scan3(const int* __restrict__ ex, const int* __restrict__ boff,
                        int* __restrict__ offs, int* __restrict__ cursor) {
    int i = blockIdx.x * 256 + threadIdx.x;
    if (i < N_NODES) {
        int o = ex[i] + boff[blockIdx.x];
        offs[i] = o;
        cursor[i] = o;
    }
    if (i == 0) offs[N_NODES] = ET;   // sum of degrees is ET by construction
}

__global__ void k_fill(const int* __restrict__ ei, int* __restrict__ cursor,
                       int* __restrict__ esrc) {
    int i = blockIdx.x * blockDim.x + threadIdx.x;
    if (i >= ET) return;
    int s, d; edge_sd(ei, i, s, d);
    int pos = atomicAdd(&cursor[d], 1);
    esrc[pos] = s;
}

// ---------------- layer 1 GEMM: h1 = x @ W1, + attention logits ----------------
// 16 nodes per 256-thread block. Thread t: feature jj=t&127, nodes half*8..half*8+7.
__global__ void k_gemm1(const float* __restrict__ x, const float* __restrict__ W1,
                        const float* __restrict__ a_s, const float* __restrict__ a_d,
                        float* __restrict__ h1, float* __restrict__ al_s,
                        float* __restrict__ al_d) {
    __shared__ float xs[16 * F_IN];      // 8 KB
    __shared__ float hv[16 * HH];        // 8 KB (raw h1 values for reductions)
    int t = threadIdx.x;
    int nb = blockIdx.x * 16;
    const float4* xv = (const float4*)(x + (size_t)nb * F_IN);
    float4* xsv = (float4*)xs;
    for (int idx = t; idx < 16 * F_IN / 4; idx += 256) xsv[idx] = xv[idx];
    __syncthreads();
    int jj = t & 127, half = t >> 7;
    float acc[8] = {0, 0, 0, 0, 0, 0, 0, 0};
    for (int k = 0; k < F_IN; ++k) {
        float w = W1[k * HH + jj];
#pragma unroll
        for (int nd = 0; nd < 8; ++nd)
            acc[nd] = fmaf(xs[(half * 8 + nd) * F_IN + k], w, acc[nd]);  // LDS broadcast
    }
#pragma unroll
    for (int nd = 0; nd < 8; ++nd) {
        int n = half * 8 + nd;
        h1[(size_t)(nb + n) * HH + jj] = acc[nd];
        hv[n * HH + jj] = acc[nd];
    }
    __syncthreads();
    if (t < 64) {
        int n = t >> 2, h = t & 3;
        float s1 = 0.f, s2 = 0.f;
        for (int i = 0; i < HID; ++i) {
            float v = hv[n * HH + h * HID + i];
            s1 = fmaf(v, a_s[h * HID + i], s1);
            s2 = fmaf(v, a_d[h * HID + i], s2);
        }
        al_s[(nb + n) * HEADS + h] = s1;
        al_d[(nb + n) * HEADS + h] = s2;
    }
}

// ---------------- layer 1 aggregate: wave per dst node, no atomics ----------------
__global__ void k_agg1(const int* __restrict__ esrc, const int* __restrict__ offs,
                       const float* __restrict__ alS, const float* __restrict__ alD,
                       const float* __restrict__ h1, const float* __restrict__ b1,
                       float* __restrict__ h1a) {
    int gid = blockIdx.x * blockDim.x + threadIdx.x;
    int n = gid >> 6;
    int lane = threadIdx.x & 63;
    if (n >= N_NODES) return;
    int off = offs[n], end = offs[n + 1];
    int h = lane >> 4;
    float ad = alD[n * 4 + h];
    // phase A: online softmax; slot = lane & 15
    float m = NEG_BIG, ssum = 0.f;
    for (int e = off + (lane & 15); e < end; e += 16) {
        int s = esrc[e];
        float ev = lrelu(alS[s * 4 + h] + ad);
        if (ev > m) { ssum = ssum * __expf(m - ev) + 1.f; m = ev; }
        else        { ssum += __expf(ev - m); }
    }
#pragma unroll
    for (int w = 1; w < 16; w <<= 1) {
        float mo = __shfl_xor(m, w);
        float so = __shfl_xor(ssum, w);
        float mn = fmaxf(m, mo);
        ssum = ssum * __expf(m - mn) + so * __expf(mo - mn);
        m = mn;
    }
    float inv_den = 1.f / ssum;
    // phase B: features 2*lane, 2*lane+1 (head = lane>>4 == h)
    const float2* h1v = (const float2*)h1;
    float2 acc = make_float2(0.f, 0.f);
    for (int e = off; e < end; ++e) {
        int s = esrc[e];
        float as = alS[s * 4 + h];
        float2 hvv = h1v[(size_t)s * 64 + lane];
        float ev = lrelu(as + ad);
        float alpha = __expf(ev - m) * inv_den;
        acc.x = fmaf(hvv.x, alpha, acc.x);
        acc.y = fmaf(hvv.y, alpha, acc.y);
    }
    float vx = acc.x + b1[2 * lane];
    float vy = acc.y + b1[2 * lane + 1];
    vx = vx > 0.f ? vx : __expf(vx) - 1.f;
    vy = vy > 0.f ? vy : __expf(vy) - 1.f;
    ((float2*)h1a)[(size_t)n * 64 + lane] = make_float2(vx, vy);
}

// ---------------- layer 2 GEMM: h2 = h1a @ W2, + logits ----------------
__global__ void k_gemm2(const float* __restrict__ h1a, const float* __restrict__ W2,
                        const float* __restrict__ a_s2, const float* __restrict__ a_d2,
                        float* __restrict__ h2, float* __restrict__ al_s2,
                        float* __restrict__ al_d2) {
    __shared__ float hs[16 * 129];
    __shared__ float w2[F_IN * NCLS];
    __shared__ float red[256];
    int t = threadIdx.x;
    int nb = blockIdx.x * 16;
    for (int idx = t; idx < F_IN * NCLS; idx += 256) w2[idx] = W2[idx];
    for (int idx = t; idx < 16 * F_IN; idx += 256) {
        int ln = idx >> 7, k = idx & 127;
        hs[ln * 129 + k] = h1a[(size_t)(nb + ln) * F_IN + k];
    }
    __syncthreads();
    int ln = t >> 4, c = t & 15;
    float acc = 0.f;
#pragma unroll
    for (int k = 0; k < F_IN; ++k)
        acc = fmaf(hs[ln * 129 + k], w2[k * NCLS + c], acc);
    int n = nb + ln;
    h2[(size_t)n * NCLS + c] = acc;
    red[t] = acc * a_s2[c];
    __syncthreads();
    for (int off = 8; off > 0; off >>= 1) { if (c < off) red[t] += red[t + off]; __syncthreads(); }
    float asv = red[ln * 16];
    __syncthreads();
    red[t] = acc * a_d2[c];
    __syncthreads();
    for (int off = 8; off > 0; off >>= 1) { if (c < off) red[t] += red[t + off]; __syncthreads(); }
    if (c == 0) { al_s2[n] = asv; al_d2[n] = red[t]; }
}

// ---------------- layer 2 aggregate + bias + log_softmax -> out ----------------
__global__ void k_agg2(const int* __restrict__ esrc, const int* __restrict__ offs,
                       const float* __restrict__ alS2, const float* __restrict__ alD2,
                       const float* __restrict__ h2, const float* __restrict__ b2,
                       float* __restrict__ out) {
    int gid = blockIdx.x * blockDim.x + threadIdx.x;
    int n = gid >> 6;
    int lane = threadIdx.x & 63;
    if (n >= N_NODES) return;
    int off = offs[n], end = offs[n + 1];
    float ad = alD2[n];
    float m = NEG_BIG, ssum = 0.f;
    for (int e = off + lane; e < end; e += 64) {
        int s = esrc[e];
        float ev = lrelu(alS2[s] + ad);
        if (ev > m) { ssum = ssum * __expf(m - ev) + 1.f; m = ev; }
        else        { ssum += __expf(ev - m); }
    }
#pragma unroll
    for (int w = 1; w < 64; w <<= 1) {
        float mo = __shfl_xor(m, w);
        float so = __shfl_xor(ssum, w);
        float mn = fmaxf(m, mo);
        ssum = ssum * __expf(m - mn) + so * __expf(mo - mn);
        m = mn;
    }
    float inv_den = 1.f / ssum;
    int c = lane & 15, sub = lane >> 4;
    float acc = 0.f;
    for (int e = off + sub; e < end; e += 4) {
        int s = esrc[e];
        float ev = lrelu(alS2[s] + ad);
        float alpha = __expf(ev - m) * inv_den;
        acc = fmaf(h2[(size_t)s * NCLS + c], alpha, acc);
    }
    acc += __shfl_xor(acc, 16);
    acc += __shfl_xor(acc, 32);
    float v = acc + b2[c];
    float mx = v;
#pragma unroll
    for (int w = 1; w < 16; w <<= 1) mx = fmaxf(mx, __shfl_xor(mx, w));
    float ex = __expf(v - mx);
#pragma unroll
    for (int w = 1; w < 16; w <<= 1) ex += __shfl_xor(ex, w);
    float lse = mx + __logf(ex);
    if (lane < 16) out[(size_t)n * NCLS + lane] = v - lse;
}

extern "C" void kernel_launch(void* const* d_in, const int* in_sizes, int n_in,
                              void* d_out, int out_size, void* d_ws, size_t ws_size,
                              hipStream_t stream) {
    const float* x   = (const float*)d_in[0];
    const int*   ei  = (const int*)d_in[1];
    const float* W1  = (const float*)d_in[2];
    const float* as1 = (const float*)d_in[3];
    const float* ad1 = (const float*)d_in[4];
    const float* b1  = (const float*)d_in[5];
    const float* W2  = (const float*)d_in[6];
    const float* as2 = (const float*)d_in[7];
    const float* ad2 = (const float*)d_in[8];
    const float* b2  = (const float*)d_in[9];
    float* out = (float*)d_out;
    char* ws = (char*)d_ws;

    float* h1   = (float*)(ws);                 // N*128      = 25.6 MB
    float* h1a  = (float*)(ws + 25600000);      // N*128      = 25.6 MB
    float* alS1 = (float*)(ws + 51200000);      // N*4
    float* alD1 = (float*)(ws + 52000000);      // N*4
    float* h2   = (float*)(ws + 52800000);      // N*16       = 3.2 MB
    float* alS2 = (float*)(ws + 56000000);      // N
    float* alD2 = (float*)(ws + 56200000);      // N
    int*   deg  = (int*)  (ws + 56400000);      // N
    int*   offs = (int*)  (ws + 56600000);      // N+1
    int*   curs = (int*)  (ws + 56810000);      // N
    int*   esrc = (int*)  (ws + 57010000);      // ET = 3.4 MB
    int*   ex   = (int*)  (ws + 60420000);      // N
    int*   bsum = (int*)  (ws + 60620000);      // NB_SCAN
    int*   boff = (int*)  (ws + 60622048);      // NB_SCAN  (total ~60.7 MB)

    hipMemsetAsync(deg, 0, (size_t)N_NODES * 4, stream);
    k_deg<<<(ET + 255) / 256, 256, 0, stream>>>(ei, deg);
    k_scan1<<<NB_SCAN, 256, 0, stream>>>(deg, ex, bsum);
    k_scan2<<<1, 256, 0, stream>>>(bsum, boff);
    k_scan3<<<NB_SCAN, 256, 0, stream>>>(ex, boff, offs, curs);
    k_fill<<<(ET + 255) / 256, 256, 0, stream>>>(ei, curs, esrc);

    k_gemm1<<<N_NODES / 16, 256, 0, stream>>>(x, W1, as1, ad1, h1, alS1, alD1);
    k_agg1<<<(N_NODES * 64 + 255) / 256, 256, 0, stream>>>(esrc, offs, alS1, alD1, h1, b1, h1a);
    k_gemm2<<<N_NODES / 16, 256, 0, stream>>>(h1a, W2, as2, ad2, h2, alS2, alD2);
    k_agg2<<<(N_NODES * 64 + 255) / 256, 256, 0, stream>>>(esrc, offs, alS2, alD2, h2, b2, out);
}

// Round 5
// 330.667 us; speedup vs baseline: 3.2496x; 1.1273x over previous
//
#include <hip/hip_runtime.h>
#include <hip/hip_bf16.h>

#define N_NODES 50000
#define N_EDGES 800000
#define ET (N_EDGES + N_NODES)   // with self-loops
#define F_IN 128
#define HH 128                   // HEADS*HID
#define HEADS 4
#define HID 32
#define NCLS 16
#define NEG 0.2f
#define NB_SCAN ((N_NODES + 255) / 256)   // 196
#define MAXD 192                 // LDS-cached edge weights per node (fallback path beyond)

typedef unsigned short u16;

__device__ __forceinline__ float lrelu(float x) { return x > 0.f ? x : NEG * x; }
__device__ __forceinline__ float bu2f(u16 u) { return __uint_as_float(((unsigned)u) << 16); }
__device__ __forceinline__ u16 f2bu(float f) {
    __hip_bfloat16 h = __float2bfloat16(f);
    return *reinterpret_cast<u16*>(&h);
}

__device__ __forceinline__ void edge_sd(const int* __restrict__ ei, int i, int& s, int& d) {
    if (i < N_EDGES) { s = ei[i]; d = ei[N_EDGES + i]; }
    else             { s = i - N_EDGES; d = s; }
}

// ---------------- CSR build ----------------
__global__ void k_deg(const int* __restrict__ ei, int* __restrict__ deg) {
    int i = blockIdx.x * blockDim.x + threadIdx.x;
    if (i >= ET) return;
    int s, d; edge_sd(ei, i, s, d);
    atomicAdd(&deg[d], 1);
}

__global__ void k_scan1(const int* __restrict__ deg, int* __restrict__ ex,
                        int* __restrict__ bsum) {
    __shared__ int sh[256];
    int t = threadIdx.x;
    int i = blockIdx.x * 256 + t;
    int v = (i < N_NODES) ? deg[i] : 0;
    sh[t] = v;
    __syncthreads();
    for (int off = 1; off < 256; off <<= 1) {
        int u = (t >= off) ? sh[t - off] : 0;
        __syncthreads();
        sh[t] += u;
        __syncthreads();
    }
    if (i < N_NODES) ex[i] = sh[t] - v;
    if (t == 255) bsum[blockIdx.x] = sh[255];
}

__global__ void k_scan2(const int* __restrict__ bsum, int* __restrict__ boff) {
    __shared__ int sh[256];
    int t = threadIdx.x;
    int v = (t < NB_SCAN) ? bsum[t] : 0;
    sh[t] = v;
    __syncthreads();
    for (int off = 1; off < 256; off <<= 1) {
        int u = (t >= off) ? sh[t - off] : 0;
        __syncthreads();
        sh[t] += u;
        __syncthreads();
    }
    if (t < NB_SCAN) boff[t] = sh[t] - v;
}

__global__ void k_scan3(const int* __restrict__ ex, const int* __restrict__ boff,
                        int* __restrict__ offs, int* __restrict__ cursor) {
    int i = blockIdx.x * 256 + threadIdx.x;
    if (i < N_NODES) {
        int o = ex[i] + boff[blockIdx.x];
        offs[i] = o;
        cursor[i] = o;
    }
    if (i == 0) offs[N_NODES] = ET;
}

__global__ void k_fill(const int* __restrict__ ei, int* __restrict__ cursor,
                       int* __restrict__ esrc) {
    int i = blockIdx.x * blockDim.x + threadIdx.x;
    if (i >= ET) return;
    int s, d; edge_sd(ei, i, s, d);
    int pos = atomicAdd(&cursor[d], 1);
    esrc[pos] = s;
}

// ---------------- layer 1 GEMM: h1 (bf16) = x @ W1, + attention logits ----------------
__global__ void k_gemm1(const float* __restrict__ x, const float* __restrict__ W1,
                        const float* __restrict__ a_s, const float* __restrict__ a_d,
                        u16* __restrict__ h1b, float* __restrict__ al_s,
                        float* __restrict__ al_d) {
    __shared__ float xs[16 * F_IN];
    __shared__ float hv[16 * HH];
    int t = threadIdx.x;
    int nb = blockIdx.x * 16;
    const float4* xv = (const float4*)(x + (size_t)nb * F_IN);
    float4* xsv = (float4*)xs;
    for (int idx = t; idx < 16 * F_IN / 4; idx += 256) xsv[idx] = xv[idx];
    __syncthreads();
    int jj = t & 127, half = t >> 7;
    float acc[8] = {0, 0, 0, 0, 0, 0, 0, 0};
    for (int k = 0; k < F_IN; ++k) {
        float w = W1[k * HH + jj];
#pragma unroll
        for (int nd = 0; nd < 8; ++nd)
            acc[nd] = fmaf(xs[(half * 8 + nd) * F_IN + k], w, acc[nd]);
    }
#pragma unroll
    for (int nd = 0; nd < 8; ++nd) {
        int n = half * 8 + nd;
        h1b[(size_t)(nb + n) * HH + jj] = f2bu(acc[nd]);
        hv[n * HH + jj] = acc[nd];
    }
    __syncthreads();
    if (t < 64) {
        int n = t >> 2, h = t & 3;
        float s1 = 0.f, s2 = 0.f;
        for (int i = 0; i < HID; ++i) {
            float v = hv[n * HH + h * HID + i];
            s1 = fmaf(v, a_s[h * HID + i], s1);
            s2 = fmaf(v, a_d[h * HID + i], s2);
        }
        al_s[(nb + n) * HEADS + h] = s1;
        al_d[(nb + n) * HEADS + h] = s2;
    }
}

// ---------------- layer 1 aggregate: wave per dst node ----------------
// phase A: per-edge softmax weights (no max-subtraction; logits are O(1)) cached in LDS
// phase B: 2 edges in flight per wave, bf16x4 gather, fp32 accumulate
__global__ void __launch_bounds__(256) k_agg1(
        const int* __restrict__ esrc, const int* __restrict__ offs,
        const float* __restrict__ alS, const float* __restrict__ alD,
        const u16* __restrict__ h1b, const float* __restrict__ b1,
        float* __restrict__ h1a) {
    __shared__ float wls[4][MAXD * HEADS];   // 12 KB
    int wave = threadIdx.x >> 6;
    int lane = threadIdx.x & 63;
    int n = blockIdx.x * 4 + wave;           // grid is exactly N/4 blocks
    int off = offs[n], end = offs[n + 1];
    // phase A: slot = lane&15, head = lane>>4
    int slot = lane & 15, h = lane >> 4;
    float ad = alD[n * 4 + h];
    float den = 0.f;
    for (int e = off + slot; e < end; e += 16) {
        int s = esrc[e];
        float wv = __expf(lrelu(alS[s * 4 + h] + ad));
        int idx = e - off;
        if (idx < MAXD) wls[wave][idx * 4 + h] = wv;
        den += wv;
    }
#pragma unroll
    for (int w = 1; w < 16; w <<= 1) den += __shfl_xor(den, w);
    float inv = 1.f / den;                   // valid in all lanes of head group
    __syncthreads();
    // phase B: half-wave per edge; features 4*fl..4*fl+3, head = fl>>3
    int half = lane >> 5, fl = lane & 31;
    int hb = fl >> 3;
    float invh = __shfl(inv, hb << 4);
    float adh = alD[n * 4 + hb];
    float4 acc = make_float4(0.f, 0.f, 0.f, 0.f);
    for (int e = off + half; e < end; e += 2) {
        int s = esrc[e];
        int idx = e - off;
        float wv = (idx < MAXD) ? wls[wave][idx * 4 + hb]
                                : __expf(lrelu(alS[s * 4 + hb] + adh));
        float a = wv * invh;
        ushort4 q = ((const ushort4*)(h1b + (size_t)s * HH))[fl];
        acc.x = fmaf(bu2f(q.x), a, acc.x);
        acc.y = fmaf(bu2f(q.y), a, acc.y);
        acc.z = fmaf(bu2f(q.z), a, acc.z);
        acc.w = fmaf(bu2f(q.w), a, acc.w);
    }
    acc.x += __shfl_xor(acc.x, 32);
    acc.y += __shfl_xor(acc.y, 32);
    acc.z += __shfl_xor(acc.z, 32);
    acc.w += __shfl_xor(acc.w, 32);
    if (half == 0) {
        float4 bb = ((const float4*)b1)[fl];
        float vx = acc.x + bb.x, vy = acc.y + bb.y, vz = acc.z + bb.z, vw = acc.w + bb.w;
        vx = vx > 0.f ? vx : __expf(vx) - 1.f;
        vy = vy > 0.f ? vy : __expf(vy) - 1.f;
        vz = vz > 0.f ? vz : __expf(vz) - 1.f;
        vw = vw > 0.f ? vw : __expf(vw) - 1.f;
        ((float4*)(h1a + (size_t)n * HH))[fl] = make_float4(vx, vy, vz, vw);
    }
}

// ---------------- layer 2 GEMM: h2 = h1a @ W2, + logits ----------------
__global__ void k_gemm2(const float* __restrict__ h1a, const float* __restrict__ W2,
                        const float* __restrict__ a_s2, const float* __restrict__ a_d2,
                        float* __restrict__ h2, float* __restrict__ al_s2,
                        float* __restrict__ al_d2) {
    __shared__ float hs[16 * 129];
    __shared__ float w2[F_IN * NCLS];
    __shared__ float red[256];
    int t = threadIdx.x;
    int nb = blockIdx.x * 16;
    for (int idx = t; idx < F_IN * NCLS; idx += 256) w2[idx] = W2[idx];
    for (int idx = t; idx < 16 * F_IN; idx += 256) {
        int ln = idx >> 7, k = idx & 127;
        hs[ln * 129 + k] = h1a[(size_t)(nb + ln) * F_IN + k];
    }
    __syncthreads();
    int ln = t >> 4, c = t & 15;
    float acc = 0.f;
#pragma unroll
    for (int k = 0; k < F_IN; ++k)
        acc = fmaf(hs[ln * 129 + k], w2[k * NCLS + c], acc);
    int n = nb + ln;
    h2[(size_t)n * NCLS + c] = acc;
    red[t] = acc * a_s2[c];
    __syncthreads();
    for (int off = 8; off > 0; off >>= 1) { if (c < off) red[t] += red[t + off]; __syncthreads(); }
    float asv = red[ln * 16];
    __syncthreads();
    red[t] = acc * a_d2[c];
    __syncthreads();
    for (int off = 8; off > 0; off >>= 1) { if (c < off) red[t] += red[t + off]; __syncthreads(); }
    if (c == 0) { al_s2[n] = asv; al_d2[n] = red[t]; }
}

// ---------------- layer 2 aggregate + bias + log_softmax -> out ----------------
__global__ void __launch_bounds__(256) k_agg2(
        const int* __restrict__ esrc, const int* __restrict__ offs,
        const float* __restrict__ alS2, const float* __restrict__ alD2,
        const float* __restrict__ h2, const float* __restrict__ b2,
        float* __restrict__ out) {
    __shared__ float wls[4][MAXD];   // 3 KB
    int wave = threadIdx.x >> 6;
    int lane = threadIdx.x & 63;
    int n = blockIdx.x * 4 + wave;
    int off = offs[n], end = offs[n + 1];
    float ad = alD2[n];
    float den = 0.f;
    for (int e = off + lane; e < end; e += 64) {
        int s = esrc[e];
        float wv = __expf(lrelu(alS2[s] + ad));
        int idx = e - off;
        if (idx < MAXD) wls[wave][idx] = wv;
        den += wv;
    }
#pragma unroll
    for (int w = 1; w < 64; w <<= 1) den += __shfl_xor(den, w);
    float inv = 1.f / den;
    __syncthreads();
    int c = lane & 15, sub = lane >> 4;
    float acc = 0.f;
    for (int e = off + sub; e < end; e += 4) {
        int s = esrc[e];
        int idx = e - off;
        float wv = (idx < MAXD) ? wls[wave][idx] : __expf(lrelu(alS2[s] + ad));
        acc = fmaf(h2[(size_t)s * NCLS + c], wv * inv, acc);
    }
    acc += __shfl_xor(acc, 16);
    acc += __shfl_xor(acc, 32);
    float v = acc + b2[c];
    float mx = v;
#pragma unroll
    for (int w = 1; w < 16; w <<= 1) mx = fmaxf(mx, __shfl_xor(mx, w));
    float ex = __expf(v - mx);
#pragma unroll
    for (int w = 1; w < 16; w <<= 1) ex += __shfl_xor(ex, w);
    float lse = mx + __logf(ex);
    if (lane < 16) out[(size_t)n * NCLS + lane] = v - lse;
}

extern "C" void kernel_launch(void* const* d_in, const int* in_sizes, int n_in,
                              void* d_out, int out_size, void* d_ws, size_t ws_size,
                              hipStream_t stream) {
    const float* x   = (const float*)d_in[0];
    const int*   ei  = (const int*)d_in[1];
    const float* W1  = (const float*)d_in[2];
    const float* as1 = (const float*)d_in[3];
    const float* ad1 = (const float*)d_in[4];
    const float* b1  = (const float*)d_in[5];
    const float* W2  = (const float*)d_in[6];
    const float* as2 = (const float*)d_in[7];
    const float* ad2 = (const float*)d_in[8];
    const float* b2  = (const float*)d_in[9];
    float* out = (float*)d_out;
    char* ws = (char*)d_ws;

    u16*   h1b  = (u16*)  (ws);                 // N*128 bf16 = 12.8 MB
    float* h1a  = (float*)(ws + 12800000);      // N*128 f32  = 25.6 MB
    float* alS1 = (float*)(ws + 38400000);      // N*4
    float* alD1 = (float*)(ws + 39200000);      // N*4
    float* h2   = (float*)(ws + 40000000);      // N*16 = 3.2 MB
    float* alS2 = (float*)(ws + 43200000);      // N
    float* alD2 = (float*)(ws + 43400000);      // N
    int*   deg  = (int*)  (ws + 43600000);      // N
    int*   offs = (int*)  (ws + 43800000);      // N+1
    int*   curs = (int*)  (ws + 44000032);      // N
    int*   esrc = (int*)  (ws + 44200032);      // ET = 3.4 MB
    int*   ex   = (int*)  (ws + 47600032);      // N
    int*   bsum = (int*)  (ws + 47800032);      // NB_SCAN
    int*   boff = (int*)  (ws + 47801056);      // NB_SCAN   (total ~47.9 MB)

    hipMemsetAsync(deg, 0, (size_t)N_NODES * 4, stream);
    k_deg<<<(ET + 255) / 256, 256, 0, stream>>>(ei, deg);
    k_scan1<<<NB_SCAN, 256, 0, stream>>>(deg, ex, bsum);
    k_scan2<<<1, 256, 0, stream>>>(bsum, boff);
    k_scan3<<<NB_SCAN, 256, 0, stream>>>(ex, boff, offs, curs);
    k_fill<<<(ET + 255) / 256, 256, 0, stream>>>(ei, curs, esrc);

    k_gemm1<<<N_NODES / 16, 256, 0, stream>>>(x, W1, as1, ad1, h1b, alS1, alD1);
    k_agg1<<<N_NODES / 4, 256, 0, stream>>>(esrc, offs, alS1, alD1, h1b, b1, h1a);
    k_gemm2<<<N_NODES / 16, 256, 0, stream>>>(h1a, W2, as2, ad2, h2, alS2, alD2);
    k_agg2<<<N_NODES / 4, 256, 0, stream>>>(esrc, offs, alS2, alD2, h2, b2, out);
}

// Round 6
// 321.646 us; speedup vs baseline: 3.3407x; 1.0280x over previous
//
#include <hip/hip_runtime.h>
#include <hip/hip_bf16.h>

#define N_NODES 50000
#define N_EDGES 800000
#define ET (N_EDGES + N_NODES)   // with self-loops
#define F_IN 128
#define HH 128                   // HEADS*HID
#define HEADS 4
#define HID 32
#define NCLS 16
#define NEG 0.2f
#define NB_SCAN ((N_NODES + 255) / 256)   // 196
#define MAXD 192                 // LDS-cached edge weights per node (fallback beyond)

typedef unsigned short u16;
typedef short bf16x8 __attribute__((ext_vector_type(8)));
typedef float f32x4 __attribute__((ext_vector_type(4)));

__device__ __forceinline__ float lrelu(float x) { return x > 0.f ? x : NEG * x; }
__device__ __forceinline__ float bu2f(u16 u) { return __uint_as_float(((unsigned)u) << 16); }
__device__ __forceinline__ u16 f2bu(float f) {
    __hip_bfloat16 h = __float2bfloat16(f);
    return *reinterpret_cast<u16*>(&h);
}

__device__ __forceinline__ void edge_sd(const int* __restrict__ ei, int i, int& s, int& d) {
    if (i < N_EDGES) { s = ei[i]; d = ei[N_EDGES + i]; }
    else             { s = i - N_EDGES; d = s; }
}

// ---------------- CSR build ----------------
__global__ void k_deg(const int* __restrict__ ei, int* __restrict__ deg) {
    int i = blockIdx.x * blockDim.x + threadIdx.x;
    if (i >= ET) return;
    int s, d; edge_sd(ei, i, s, d);
    atomicAdd(&deg[d], 1);
}

__global__ void k_scan1(const int* __restrict__ deg, int* __restrict__ ex,
                        int* __restrict__ bsum) {
    __shared__ int sh[256];
    int t = threadIdx.x;
    int i = blockIdx.x * 256 + t;
    int v = (i < N_NODES) ? deg[i] : 0;
    sh[t] = v;
    __syncthreads();
    for (int off = 1; off < 256; off <<= 1) {
        int u = (t >= off) ? sh[t - off] : 0;
        __syncthreads();
        sh[t] += u;
        __syncthreads();
    }
    if (i < N_NODES) ex[i] = sh[t] - v;
    if (t == 255) bsum[blockIdx.x] = sh[255];
}

__global__ void k_scan2(const int* __restrict__ bsum, int* __restrict__ boff) {
    __shared__ int sh[256];
    int t = threadIdx.x;
    int v = (t < NB_SCAN) ? bsum[t] : 0;
    sh[t] = v;
    __syncthreads();
    for (int off = 1; off < 256; off <<= 1) {
        int u = (t >= off) ? sh[t - off] : 0;
        __syncthreads();
        sh[t] += u;
        __syncthreads();
    }
    if (t < NB_SCAN) boff[t] = sh[t] - v;
}

__global__ void k_scan3(const int* __restrict__ ex, const int* __restrict__ boff,
                        int* __restrict__ offs, int* __restrict__ cursor) {
    int i = blockIdx.x * 256 + threadIdx.x;
    if (i < N_NODES) {
        int o = ex[i] + boff[blockIdx.x];
        offs[i] = o;
        cursor[i] = o;
    }
    if (i == 0) offs[N_NODES] = ET;
}

__global__ void k_fill(const int* __restrict__ ei, int* __restrict__ cursor,
                       int* __restrict__ esrc) {
    int i = blockIdx.x * blockDim.x + threadIdx.x;
    if (i >= ET) return;
    int s, d; edge_sd(ei, i, s, d);
    int pos = atomicAdd(&cursor[d], 1);
    esrc[pos] = s;
}

// ---------------- layer 1 GEMM via MFMA: h1b (bf16) = x @ W1, + logits ----------------
// 256 thr = 4 waves; each wave one 16-node tile; W1^T staged bf16 in LDS.
__global__ void __launch_bounds__(256) k_gemm1(
        const float* __restrict__ x, const float* __restrict__ W1,
        const float* __restrict__ a_s, const float* __restrict__ a_d,
        u16* __restrict__ h1b, float* __restrict__ al_s, float* __restrict__ al_d) {
    __shared__ u16 w1t[128 * 136];   // w1t[n][k], stride 136 (272B, 16B-aligned rows)
    int t = threadIdx.x;
    for (int it = 0; it < 64; ++it) {
        int idx = it * 256 + t;              // idx = k*128 + n
        int k = idx >> 7, n = idx & 127;
        w1t[n * 136 + k] = f2bu(W1[idx]);    // coalesced global read
    }
    __syncthreads();
    int wave = t >> 6, lane = t & 63;
    int col = lane & 15, quad = lane >> 4;
    int tb = blockIdx.x * 64 + wave * 16;
    // A fragments: node = tb+col, k = kb*32 + quad*8 + j
    union { bf16x8 v; u16 u[8]; } af[4];
    int anode = tb + col;
    bool aval = anode < N_NODES;
    const float* xr = x + (size_t)anode * F_IN + quad * 8;
#pragma unroll
    for (int kb = 0; kb < 4; ++kb) {
        float4 lo = aval ? ((const float4*)(xr + kb * 32))[0] : make_float4(0.f, 0.f, 0.f, 0.f);
        float4 hi = aval ? ((const float4*)(xr + kb * 32))[1] : make_float4(0.f, 0.f, 0.f, 0.f);
        af[kb].u[0] = f2bu(lo.x); af[kb].u[1] = f2bu(lo.y);
        af[kb].u[2] = f2bu(lo.z); af[kb].u[3] = f2bu(lo.w);
        af[kb].u[4] = f2bu(hi.x); af[kb].u[5] = f2bu(hi.y);
        af[kb].u[6] = f2bu(hi.z); af[kb].u[7] = f2bu(hi.w);
    }
    float ps[4][4] = {}, pd[4][4] = {};
#pragma unroll
    for (int nt = 0; nt < 8; ++nt) {
        f32x4 acc = {0.f, 0.f, 0.f, 0.f};
#pragma unroll
        for (int kb = 0; kb < 4; ++kb) {
            bf16x8 bf = *(const bf16x8*)&w1t[(nt * 16 + col) * 136 + kb * 32 + quad * 8];
            acc = __builtin_amdgcn_mfma_f32_16x16x32_bf16(af[kb].v, bf, acc, 0, 0, 0);
        }
        int feat = nt * 16 + col;
        float asv = a_s[feat], adv = a_d[feat];
        const int head = nt >> 1;              // feats [nt*16, nt*16+16) all in head nt/2
#pragma unroll
        for (int r = 0; r < 4; ++r) {
            int node = tb + quad * 4 + r;      // D layout: row = quad*4 + reg
            float v = acc[r];
            if (node < N_NODES) h1b[(size_t)node * HH + feat] = f2bu(v);
            ps[r][head] = fmaf(v, asv, ps[r][head]);
            pd[r][head] = fmaf(v, adv, pd[r][head]);
        }
    }
    // reduce logit partials across the 16 col-lanes
#pragma unroll
    for (int r = 0; r < 4; ++r)
#pragma unroll
        for (int h = 0; h < 4; ++h)
#pragma unroll
            for (int w = 1; w < 16; w <<= 1) {
                ps[r][h] += __shfl_xor(ps[r][h], w);
                pd[r][h] += __shfl_xor(pd[r][h], w);
            }
    if (col == 0) {
#pragma unroll
        for (int r = 0; r < 4; ++r) {
            int node = tb + quad * 4 + r;
            if (node < N_NODES) {
#pragma unroll
                for (int h = 0; h < 4; ++h) {
                    al_s[node * 4 + h] = ps[r][h];
                    al_d[node * 4 + h] = pd[r][h];
                }
            }
        }
    }
}

// ---------------- layer 1 aggregate + fused layer-2 GEMM + layer-2 logits ----------------
__global__ void __launch_bounds__(256) k_agg1(
        const int* __restrict__ esrc, const int* __restrict__ offs,
        const float* __restrict__ alS, const float* __restrict__ alD,
        const u16* __restrict__ h1b, const float* __restrict__ b1,
        const float* __restrict__ W2, const float* __restrict__ a_s2,
        const float* __restrict__ a_d2,
        float* __restrict__ h2, float* __restrict__ alS2, float* __restrict__ alD2) {
    __shared__ float wls[4][MAXD * HEADS];       // 12 KB
    __shared__ __align__(16) float rowf[4][HH];  // 2 KB
    __shared__ float w2s[F_IN * 17];             // 8.7 KB, padded stride 17
    __shared__ float as2s[NCLS], ad2s[NCLS];
    int t = threadIdx.x;
    for (int idx = t; idx < F_IN * NCLS; idx += 256)
        w2s[(idx >> 4) * 17 + (idx & 15)] = W2[idx];
    if (t < NCLS) { as2s[t] = a_s2[t]; ad2s[t] = a_d2[t]; }
    __syncthreads();
    int wave = t >> 6;
    int lane = t & 63;
    int n = blockIdx.x * 4 + wave;               // grid = N/4 exactly
    int off = offs[n], end = offs[n + 1];
    // phase A: softmax weights (no max-sub; logits O(1)); slot=lane&15, head=lane>>4
    int slot = lane & 15, h = lane >> 4;
    float ad = alD[n * 4 + h];
    float den = 0.f;
    for (int e = off + slot; e < end; e += 16) {
        int s = esrc[e];
        float wv = __expf(lrelu(alS[s * 4 + h] + ad));
        int idx = e - off;
        if (idx < MAXD) wls[wave][idx * 4 + h] = wv;
        den += wv;
    }
#pragma unroll
    for (int w = 1; w < 16; w <<= 1) den += __shfl_xor(den, w);
    float inv = 1.f / den;
    // phase B: half-wave per edge; features 4*fl..4*fl+3, head hb = fl>>3
    int half = lane >> 5, fl = lane & 31;
    int hb = fl >> 3;
    float invh = __shfl(inv, hb << 4);
    float adh = alD[n * 4 + hb];
    float4 acc = make_float4(0.f, 0.f, 0.f, 0.f);
    for (int e = off + half; e < end; e += 2) {
        int s = esrc[e];
        int idx = e - off;
        float wv = (idx < MAXD) ? wls[wave][idx * 4 + hb]
                                : __expf(lrelu(alS[s * 4 + hb] + adh));
        float a = wv * invh;
        ushort4 q4 = ((const ushort4*)(h1b + (size_t)s * HH))[fl];
        acc.x = fmaf(bu2f(q4.x), a, acc.x);
        acc.y = fmaf(bu2f(q4.y), a, acc.y);
        acc.z = fmaf(bu2f(q4.z), a, acc.z);
        acc.w = fmaf(bu2f(q4.w), a, acc.w);
    }
    acc.x += __shfl_xor(acc.x, 32);
    acc.y += __shfl_xor(acc.y, 32);
    acc.z += __shfl_xor(acc.z, 32);
    acc.w += __shfl_xor(acc.w, 32);
    if (half == 0) {
        float4 bb = ((const float4*)b1)[fl];
        float vx = acc.x + bb.x, vy = acc.y + bb.y, vz = acc.z + bb.z, vw = acc.w + bb.w;
        vx = vx > 0.f ? vx : __expf(vx) - 1.f;
        vy = vy > 0.f ? vy : __expf(vy) - 1.f;
        vz = vz > 0.f ? vz : __expf(vz) - 1.f;
        vw = vw > 0.f ? vw : __expf(vw) - 1.f;
        ((float4*)&rowf[wave][0])[fl] = make_float4(vx, vy, vz, vw);
    }
    // fused gemm2: h2[n] = rowf @ W2 (same wave -> no barrier needed)
    int c = lane & 15, q = lane >> 4;
    float h2acc = 0.f;
#pragma unroll
    for (int i = 0; i < 32; ++i) {
        int f = q * 32 + i;
        h2acc = fmaf(rowf[wave][f], w2s[f * 17 + c], h2acc);
    }
    h2acc += __shfl_xor(h2acc, 16);
    h2acc += __shfl_xor(h2acc, 32);
    if (lane < 16) h2[(size_t)n * NCLS + lane] = h2acc;
    float rs = h2acc * as2s[c], rd = h2acc * ad2s[c];
#pragma unroll
    for (int w = 1; w < 16; w <<= 1) { rs += __shfl_xor(rs, w); rd += __shfl_xor(rd, w); }
    if (lane == 0) { alS2[n] = rs; alD2[n] = rd; }
}

// ---------------- layer 2 aggregate + bias + log_softmax -> out ----------------
__global__ void __launch_bounds__(256) k_agg2(
        const int* __restrict__ esrc, const int* __restrict__ offs,
        const float* __restrict__ alS2, const float* __restrict__ alD2,
        const float* __restrict__ h2, const float* __restrict__ b2,
        float* __restrict__ out) {
    __shared__ float wls[4][MAXD];
    int wave = threadIdx.x >> 6;
    int lane = threadIdx.x & 63;
    int n = blockIdx.x * 4 + wave;
    int off = offs[n], end = offs[n + 1];
    float ad = alD2[n];
    float den = 0.f;
    for (int e = off + lane; e < end; e += 64) {
        int s = esrc[e];
        float wv = __expf(lrelu(alS2[s] + ad));
        int idx = e - off;
        if (idx < MAXD) wls[wave][idx] = wv;
        den += wv;
    }
#pragma unroll
    for (int w = 1; w < 64; w <<= 1) den += __shfl_xor(den, w);
    float inv = 1.f / den;
    __syncthreads();
    int c = lane & 15, sub = lane >> 4;
    float acc = 0.f;
    for (int e = off + sub; e < end; e += 4) {
        int s = esrc[e];
        int idx = e - off;
        float wv = (idx < MAXD) ? wls[wave][idx] : __expf(lrelu(alS2[s] + ad));
        acc = fmaf(h2[(size_t)s * NCLS + c], wv * inv, acc);
    }
    acc += __shfl_xor(acc, 16);
    acc += __shfl_xor(acc, 32);
    float v = acc + b2[c];
    float mx = v;
#pragma unroll
    for (int w = 1; w < 16; w <<= 1) mx = fmaxf(mx, __shfl_xor(mx, w));
    float ex = __expf(v - mx);
#pragma unroll
    for (int w = 1; w < 16; w <<= 1) ex += __shfl_xor(ex, w);
    float lse = mx + __logf(ex);
    if (lane < 16) out[(size_t)n * NCLS + lane] = v - lse;
}

extern "C" void kernel_launch(void* const* d_in, const int* in_sizes, int n_in,
                              void* d_out, int out_size, void* d_ws, size_t ws_size,
                              hipStream_t stream) {
    const float* x   = (const float*)d_in[0];
    const int*   ei  = (const int*)d_in[1];
    const float* W1  = (const float*)d_in[2];
    const float* as1 = (const float*)d_in[3];
    const float* ad1 = (const float*)d_in[4];
    const float* b1  = (const float*)d_in[5];
    const float* W2  = (const float*)d_in[6];
    const float* as2 = (const float*)d_in[7];
    const float* ad2 = (const float*)d_in[8];
    const float* b2  = (const float*)d_in[9];
    float* out = (float*)d_out;
    char* ws = (char*)d_ws;

    u16*   h1b  = (u16*)  (ws);                 // N*128 bf16 = 12.8 MB
    float* alS1 = (float*)(ws + 12800000);      // N*4
    float* alD1 = (float*)(ws + 13600000);      // N*4
    float* h2   = (float*)(ws + 14400000);      // N*16 = 3.2 MB
    float* alS2 = (float*)(ws + 17600000);      // N
    float* alD2 = (float*)(ws + 17800000);      // N
    int*   deg  = (int*)  (ws + 18000000);      // N
    int*   offs = (int*)  (ws + 18200000);      // N+1
    int*   curs = (int*)  (ws + 18400064);      // N
    int*   esrc = (int*)  (ws + 18600064);      // ET = 3.4 MB
    int*   ex   = (int*)  (ws + 22000064);      // N
    int*   bsum = (int*)  (ws + 22200064);      // NB_SCAN
    int*   boff = (int*)  (ws + 22201088);      // NB_SCAN  (total ~22.2 MB)

    hipMemsetAsync(deg, 0, (size_t)N_NODES * 4, stream);
    k_deg<<<(ET + 255) / 256, 256, 0, stream>>>(ei, deg);
    k_scan1<<<NB_SCAN, 256, 0, stream>>>(deg, ex, bsum);
    k_scan2<<<1, 256, 0, stream>>>(bsum, boff);
    k_scan3<<<NB_SCAN, 256, 0, stream>>>(ex, boff, offs, curs);
    k_fill<<<(ET + 255) / 256, 256, 0, stream>>>(ei, curs, esrc);

    k_gemm1<<<(N_NODES + 63) / 64, 256, 0, stream>>>(x, W1, as1, ad1, h1b, alS1, alD1);
    k_agg1<<<N_NODES / 4, 256, 0, stream>>>(esrc, offs, alS1, alD1, h1b, b1,
                                            W2, as2, ad2, h2, alS2, alD2);
    k_agg2<<<N_NODES / 4, 256, 0, stream>>>(esrc, offs, alS2, alD2, h2, b2, out);
}

// Round 7
// 289.275 us; speedup vs baseline: 3.7145x; 1.1119x over previous
//
#include <hip/hip_runtime.h>
#include <hip/hip_bf16.h>

#define N_NODES 50000
#define N_EDGES 800000
#define ET (N_EDGES + N_NODES)   // with self-loops
#define F_IN 128
#define HH 128                   // HEADS*HID
#define HEADS 4
#define HID 32
#define NCLS 16
#define NEG 0.2f
#define NB_SCAN ((N_NODES + 255) / 256)   // 196
#define MAXD 64                  // LDS-cached edge weights per node (recompute fallback beyond)

typedef unsigned short u16;
typedef short bf16x8 __attribute__((ext_vector_type(8)));
typedef float f32x4 __attribute__((ext_vector_type(4)));
typedef u16 u16x8 __attribute__((ext_vector_type(8)));

__device__ __forceinline__ float lrelu(float x) { return x > 0.f ? x : NEG * x; }
__device__ __forceinline__ float bu2f(u16 u) { return __uint_as_float(((unsigned)u) << 16); }
__device__ __forceinline__ u16 f2bu(float f) {
    __hip_bfloat16 h = __float2bfloat16(f);
    return *reinterpret_cast<u16*>(&h);
}

__device__ __forceinline__ void edge_sd(const int* __restrict__ ei, int i, int& s, int& d) {
    if (i < N_EDGES) { s = ei[i]; d = ei[N_EDGES + i]; }
    else             { s = i - N_EDGES; d = s; }
}

// ---------------- CSR build ----------------
__global__ void k_deg(const int* __restrict__ ei, int* __restrict__ deg) {
    int i = blockIdx.x * blockDim.x + threadIdx.x;
    if (i >= ET) return;
    int s, d; edge_sd(ei, i, s, d);
    atomicAdd(&deg[d], 1);
}

__global__ void k_scan1(const int* __restrict__ deg, int* __restrict__ ex,
                        int* __restrict__ bsum) {
    __shared__ int sh[256];
    int t = threadIdx.x;
    int i = blockIdx.x * 256 + t;
    int v = (i < N_NODES) ? deg[i] : 0;
    sh[t] = v;
    __syncthreads();
    for (int off = 1; off < 256; off <<= 1) {
        int u = (t >= off) ? sh[t - off] : 0;
        __syncthreads();
        sh[t] += u;
        __syncthreads();
    }
    if (i < N_NODES) ex[i] = sh[t] - v;
    if (t == 255) bsum[blockIdx.x] = sh[255];
}

__global__ void k_scan2(const int* __restrict__ bsum, int* __restrict__ boff) {
    __shared__ int sh[256];
    int t = threadIdx.x;
    int v = (t < NB_SCAN) ? bsum[t] : 0;
    sh[t] = v;
    __syncthreads();
    for (int off = 1; off < 256; off <<= 1) {
        int u = (t >= off) ? sh[t - off] : 0;
        __syncthreads();
        sh[t] += u;
        __syncthreads();
    }
    if (t < NB_SCAN) boff[t] = sh[t] - v;
}

__global__ void k_scan3(const int* __restrict__ ex, const int* __restrict__ boff,
                        int* __restrict__ offs, int* __restrict__ cursor) {
    int i = blockIdx.x * 256 + threadIdx.x;
    if (i < N_NODES) {
        int o = ex[i] + boff[blockIdx.x];
        offs[i] = o;
        cursor[i] = o;
    }
    if (i == 0) offs[N_NODES] = ET;
}

__global__ void k_fill(const int* __restrict__ ei, int* __restrict__ cursor,
                       int* __restrict__ esrc) {
    int i = blockIdx.x * blockDim.x + threadIdx.x;
    if (i >= ET) return;
    int s, d; edge_sd(ei, i, s, d);
    int pos = atomicAdd(&cursor[d], 1);
    esrc[pos] = s;
}

// ---------------- layer 1 GEMM via MFMA: h1b (bf16) = x @ W1, + logits ----------------
__global__ void __launch_bounds__(256) k_gemm1(
        const float* __restrict__ x, const float* __restrict__ W1,
        const float* __restrict__ a_s, const float* __restrict__ a_d,
        u16* __restrict__ h1b, float* __restrict__ al_s, float* __restrict__ al_d) {
    __shared__ u16 w1t[128 * 136];   // w1t[n][k], stride 136 (16B-aligned rows)
    int t = threadIdx.x;
    for (int it = 0; it < 64; ++it) {
        int idx = it * 256 + t;              // idx = k*128 + n
        int k = idx >> 7, n = idx & 127;
        w1t[n * 136 + k] = f2bu(W1[idx]);
    }
    __syncthreads();
    int wave = t >> 6, lane = t & 63;
    int col = lane & 15, quad = lane >> 4;
    int tb = blockIdx.x * 64 + wave * 16;
    union { bf16x8 v; u16 u[8]; } af[4];
    int anode = tb + col;
    bool aval = anode < N_NODES;
    const float* xr = x + (size_t)anode * F_IN + quad * 8;
#pragma unroll
    for (int kb = 0; kb < 4; ++kb) {
        float4 lo = aval ? ((const float4*)(xr + kb * 32))[0] : make_float4(0.f, 0.f, 0.f, 0.f);
        float4 hi = aval ? ((const float4*)(xr + kb * 32))[1] : make_float4(0.f, 0.f, 0.f, 0.f);
        af[kb].u[0] = f2bu(lo.x); af[kb].u[1] = f2bu(lo.y);
        af[kb].u[2] = f2bu(lo.z); af[kb].u[3] = f2bu(lo.w);
        af[kb].u[4] = f2bu(hi.x); af[kb].u[5] = f2bu(hi.y);
        af[kb].u[6] = f2bu(hi.z); af[kb].u[7] = f2bu(hi.w);
    }
    float ps[4][4] = {}, pd[4][4] = {};
#pragma unroll
    for (int nt = 0; nt < 8; ++nt) {
        f32x4 acc = {0.f, 0.f, 0.f, 0.f};
#pragma unroll
        for (int kb = 0; kb < 4; ++kb) {
            bf16x8 bf = *(const bf16x8*)&w1t[(nt * 16 + col) * 136 + kb * 32 + quad * 8];
            acc = __builtin_amdgcn_mfma_f32_16x16x32_bf16(af[kb].v, bf, acc, 0, 0, 0);
        }
        int feat = nt * 16 + col;
        float asv = a_s[feat], adv = a_d[feat];
        const int head = nt >> 1;
#pragma unroll
        for (int r = 0; r < 4; ++r) {
            int node = tb + quad * 4 + r;
            float v = acc[r];
            if (node < N_NODES) h1b[(size_t)node * HH + feat] = f2bu(v);
            ps[r][head] = fmaf(v, asv, ps[r][head]);
            pd[r][head] = fmaf(v, adv, pd[r][head]);
        }
    }
#pragma unroll
    for (int r = 0; r < 4; ++r)
#pragma unroll
        for (int h = 0; h < 4; ++h)
#pragma unroll
            for (int w = 1; w < 16; w <<= 1) {
                ps[r][h] += __shfl_xor(ps[r][h], w);
                pd[r][h] += __shfl_xor(pd[r][h], w);
            }
    if (col == 0) {
#pragma unroll
        for (int r = 0; r < 4; ++r) {
            int node = tb + quad * 4 + r;
            if (node < N_NODES) {
#pragma unroll
                for (int h = 0; h < 4; ++h) {
                    al_s[node * 4 + h] = ps[r][h];
                    al_d[node * 4 + h] = pd[r][h];
                }
            }
        }
    }
}

// ---------------- layer 1 aggregate + fused layer-2 GEMM + layer-2 logits ----------------
__global__ void __launch_bounds__(256) k_agg1(
        const int* __restrict__ esrc, const int* __restrict__ offs,
        const float* __restrict__ alS, const float* __restrict__ alD,
        const u16* __restrict__ h1b, const float* __restrict__ b1,
        const float* __restrict__ W2, const float* __restrict__ a_s2,
        const float* __restrict__ a_d2,
        float* __restrict__ h2, float* __restrict__ alS2, float* __restrict__ alD2) {
    __shared__ float wls[4][MAXD * HEADS];       // 4 KB
    __shared__ __align__(16) float rowf[4][HH];  // 2 KB
    __shared__ float w2t[NCLS * 132];            // 8.25 KB, w2t[c][f] stride 132
    __shared__ float as2s[NCLS], ad2s[NCLS];
    int t = threadIdx.x;
    for (int idx = t; idx < F_IN * NCLS; idx += 256) {
        int f = idx >> 4, c = idx & 15;
        w2t[c * 132 + f] = W2[idx];
    }
    if (t < NCLS) { as2s[t] = a_s2[t]; ad2s[t] = a_d2[t]; }
    __syncthreads();
    int wave = t >> 6;
    int lane = t & 63;
    int n = blockIdx.x * 4 + wave;               // grid = N/4 exactly
    int off = offs[n], end = offs[n + 1];
    // phase A: softmax weights (no max-sub; logits O(1)); slot=lane&15, head=lane>>4
    int slot = lane & 15, h = lane >> 4;
    float ad = alD[n * 4 + h];
    float den = 0.f;
    for (int e = off + slot; e < end; e += 16) {
        int s = esrc[e];
        float wv = __expf(lrelu(alS[s * 4 + h] + ad));
        int idx = e - off;
        if (idx < MAXD) wls[wave][idx * 4 + h] = wv;
        den += wv;
    }
#pragma unroll
    for (int w = 1; w < 16; w <<= 1) den += __shfl_xor(den, w);
    float inv = 1.f / den;
    // phase B: quarter-wave (16 lanes) per edge, 4 edges in flight.
    // lane = (quarter, fl); features 8*fl..8*fl+7, head hb = fl>>2
    int quarter = lane >> 4, fl = lane & 15;
    int hb = fl >> 2;
    float invh = __shfl(inv, hb << 4);
    float adh = alD[n * 4 + hb];
    float acc[8] = {};
    for (int e = off + quarter; e < end; e += 4) {
        int s = esrc[e];
        int idx = e - off;
        float wv = (idx < MAXD) ? wls[wave][idx * 4 + hb]
                                : __expf(lrelu(alS[s * 4 + hb] + adh));
        float a = wv * invh;
        u16x8 q8 = ((const u16x8*)(h1b + (size_t)s * HH))[fl];
#pragma unroll
        for (int j = 0; j < 8; ++j)
            acc[j] = fmaf(bu2f(q8[j]), a, acc[j]);
    }
#pragma unroll
    for (int j = 0; j < 8; ++j) {
        acc[j] += __shfl_xor(acc[j], 16);
        acc[j] += __shfl_xor(acc[j], 32);
    }
    if (quarter == 0) {
        const float4* b4 = (const float4*)b1;
        float4 blo = b4[fl * 2], bhi = b4[fl * 2 + 1];
        float v[8];
        v[0] = acc[0] + blo.x; v[1] = acc[1] + blo.y;
        v[2] = acc[2] + blo.z; v[3] = acc[3] + blo.w;
        v[4] = acc[4] + bhi.x; v[5] = acc[5] + bhi.y;
        v[6] = acc[6] + bhi.z; v[7] = acc[7] + bhi.w;
#pragma unroll
        for (int j = 0; j < 8; ++j) v[j] = v[j] > 0.f ? v[j] : __expf(v[j]) - 1.f;
        ((float4*)&rowf[wave][0])[fl * 2]     = make_float4(v[0], v[1], v[2], v[3]);
        ((float4*)&rowf[wave][0])[fl * 2 + 1] = make_float4(v[4], v[5], v[6], v[7]);
    }
    // fused gemm2 (same wave, no barrier): lane (c,q); f = 4i+q (bank-conflict-free)
    int c = lane & 15, q = lane >> 4;
    float h2acc = 0.f;
#pragma unroll
    for (int i = 0; i < 32; ++i) {
        int f = i * 4 + q;
        h2acc = fmaf(rowf[wave][f], w2t[c * 132 + f], h2acc);
    }
    h2acc += __shfl_xor(h2acc, 16);
    h2acc += __shfl_xor(h2acc, 32);
    if (lane < 16) h2[(size_t)n * NCLS + lane] = h2acc;
    float rs = h2acc * as2s[c], rd = h2acc * ad2s[c];
#pragma unroll
    for (int w = 1; w < 16; w <<= 1) { rs += __shfl_xor(rs, w); rd += __shfl_xor(rd, w); }
    if (lane == 0) { alS2[n] = rs; alD2[n] = rd; }
}

// ---------------- layer 2 aggregate + bias + log_softmax -> out ----------------
__global__ void __launch_bounds__(256) k_agg2(
        const int* __restrict__ esrc, const int* __restrict__ offs,
        const float* __restrict__ alS2, const float* __restrict__ alD2,
        const float* __restrict__ h2, const float* __restrict__ b2,
        float* __restrict__ out) {
    __shared__ float wls[4][MAXD];   // 1 KB
    int wave = threadIdx.x >> 6;
    int lane = threadIdx.x & 63;
    int n = blockIdx.x * 4 + wave;
    int off = offs[n], end = offs[n + 1];
    float ad = alD2[n];
    float den = 0.f;
    for (int e = off + lane; e < end; e += 64) {
        int s = esrc[e];
        float wv = __expf(lrelu(alS2[s] + ad));
        int idx = e - off;
        if (idx < MAXD) wls[wave][idx] = wv;
        den += wv;
    }
#pragma unroll
    for (int w = 1; w < 64; w <<= 1) den += __shfl_xor(den, w);
    float inv = 1.f / den;
    __syncthreads();
    int c = lane & 15, sub = lane >> 4;
    float acc = 0.f;
    for (int e = off + sub; e < end; e += 4) {
        int s = esrc[e];
        int idx = e - off;
        float wv = (idx < MAXD) ? wls[wave][idx] : __expf(lrelu(alS2[s] + ad));
        acc = fmaf(h2[(size_t)s * NCLS + c], wv * inv, acc);
    }
    acc += __shfl_xor(acc, 16);
    acc += __shfl_xor(acc, 32);
    float v = acc + b2[c];
    float mx = v;
#pragma unroll
    for (int w = 1; w < 16; w <<= 1) mx = fmaxf(mx, __shfl_xor(mx, w));
    float ex = __expf(v - mx);
#pragma unroll
    for (int w = 1; w < 16; w <<= 1) ex += __shfl_xor(ex, w);
    float lse = mx + __logf(ex);
    if (lane < 16) out[(size_t)n * NCLS + lane] = v - lse;
}

extern "C" void kernel_launch(void* const* d_in, const int* in_sizes, int n_in,
                              void* d_out, int out_size, void* d_ws, size_t ws_size,
                              hipStream_t stream) {
    const float* x   = (const float*)d_in[0];
    const int*   ei  = (const int*)d_in[1];
    const float* W1  = (const float*)d_in[2];
    const float* as1 = (const float*)d_in[3];
    const float* ad1 = (const float*)d_in[4];
    const float* b1  = (const float*)d_in[5];
    const float* W2  = (const float*)d_in[6];
    const float* as2 = (const float*)d_in[7];
    const float* ad2 = (const float*)d_in[8];
    const float* b2  = (const float*)d_in[9];
    float* out = (float*)d_out;
    char* ws = (char*)d_ws;

    u16*   h1b  = (u16*)  (ws);                 // N*128 bf16 = 12.8 MB
    float* alS1 = (float*)(ws + 12800000);      // N*4
    float* alD1 = (float*)(ws + 13600000);      // N*4
    float* h2   = (float*)(ws + 14400000);      // N*16 = 3.2 MB
    float* alS2 = (float*)(ws + 17600000);      // N
    float* alD2 = (float*)(ws + 17800000);      // N
    int*   deg  = (int*)  (ws + 18000000);      // N
    int*   offs = (int*)  (ws + 18200000);      // N+1
    int*   curs = (int*)  (ws + 18400064);      // N
    int*   esrc = (int*)  (ws + 18600064);      // ET = 3.4 MB
    int*   ex   = (int*)  (ws + 22000064);      // N
    int*   bsum = (int*)  (ws + 22200064);      // NB_SCAN
    int*   boff = (int*)  (ws + 22201088);      // NB_SCAN  (total ~22.2 MB)

    hipMemsetAsync(deg, 0, (size_t)N_NODES * 4, stream);
    k_deg<<<(ET + 255) / 256, 256, 0, stream>>>(ei, deg);
    k_scan1<<<NB_SCAN, 256, 0, stream>>>(deg, ex, bsum);
    k_scan2<<<1, 256, 0, stream>>>(bsum, boff);
    k_scan3<<<NB_SCAN, 256, 0, stream>>>(ex, boff, offs, curs);
    k_fill<<<(ET + 255) / 256, 256, 0, stream>>>(ei, curs, esrc);

    k_gemm1<<<(N_NODES + 63) / 64, 256, 0, stream>>>(x, W1, as1, ad1, h1b, alS1, alD1);
    k_agg1<<<N_NODES / 4, 256, 0, stream>>>(esrc, offs, alS1, alD1, h1b, b1,
                                            W2, as2, ad2, h2, alS2, alD2);
    k_agg2<<<N_NODES / 4, 256, 0, stream>>>(esrc, offs, alS2, alD2, h2, b2, out);
}